// Round 8
// baseline (26.747 us; speedup 1.0000x reference)
//
#include <hip/hip_runtime.h>

// LocallyConnected2d: out[b,o,ho,wo] = bias[o,ho,wo]
//   + sum_{c,ki,kj} x[b,c,ho+ki,wo+kj] * w[o,c,ho,wo,ki*3+kj]
//
// Round-8 = Round-7 with ONLY the VMEM issue order fixed.
//   r7 bug: body issued stage(cc+1) glds BEFORE its x loads; in-order vmcnt
//   completion means the backend's wait to consume the last x load also
//   drained the just-issued stage -> full HBM-latency stall every body
//   (this is why r5(barrier) == r7(counted vmcnt) == 26.6us).
//   Fix: per body, issue ALL 12 x loads FIRST, then stage(cc+1), then wait
//   vmcnt(21): outstanding = stage(cc)[9] + x[12] + stage(cc+1)[9] = 30;
//   vmcnt(21) drains exactly stage(cc), leaves x + next stage in flight.
//   Body 3 (no stage issue): vmcnt(12). Backend x-consumption waits now
//   leave the next stage outstanding. sched_barrier(0) pins group order;
//   no asm memory clobbers (r6 spill lesson).
//  - lane (q,l): l=lane&15 owns wo=4l..4l+3 (f4+f2, no cross-lane);
//    q=lane>>4 owns b=2q,2q+1. Weights: 9x ds_read_b128 per body.
//  - epilogue: stash partials to buf0 (body3 reads buf1; stage3 drained at
//    body3's wait -> no extra vmcnt needed), ONE __syncthreads, reduce.

#define BB 8
#define CC 16
#define HH 64
#define WW 64
#define OO 32
#define HO 62
#define WO 62
#define NLOC (HO * WO)    // 3844
#define TOTAL (OO * NLOC) // 123008

typedef float f4 __attribute__((ext_vector_type(4)));
typedef float f2 __attribute__((ext_vector_type(2)));

__device__ __forceinline__ void async_f32_to_lds(const float* g, float* l) {
  __builtin_amdgcn_global_load_lds((const __attribute__((address_space(1))) void*)g,
                                   (__attribute__((address_space(3))) void*)l,
                                   4, 0, 0);
}

__global__ __launch_bounds__(256) void lc2d_kernel(
    const float* __restrict__ x, const float* __restrict__ weight,
    const float* __restrict__ bias, float* __restrict__ out) {
  // per wave: two 576-float weight buffers; buf0 reused for partial stash
  __shared__ __align__(16) float smem[4 * 2 * 576];

  const int tid  = threadIdx.x;
  const int lane = tid & 63;
  const int wave = tid >> 6;
  const int l = lane & 15;   // wo-group: wo = 4l..4l+3
  const int q = lane >> 4;   // b-group:  b  = 2q, 2q+1
  const int ho = blockIdx.x % HO;
  const int o  = blockIdx.x / HO;

  float* buf0 = smem + wave * 1152;

  const int colbase = 4 * l;
  const int f2off = (l < 15) ? 4 : -4;  // l=15: dummy in-bounds read, discarded

  const float* wbase = weight + (size_t)(o * CC + wave * 4) * (NLOC * 9)
                              + (size_t)ho * (WO * 9);

  // ---- prologue: stage cc=0 into buf0 ----
#pragma unroll
  for (int j = 0; j < 9; ++j)
    if (j * 64 + lane < WO * 9)
      async_f32_to_lds(wbase + j * 64 + lane, buf0 + j * 64);

  f4 acc[2];
  acc[0] = (f4)0.f;
  acc[1] = (f4)0.f;

#pragma unroll
  for (int cc = 0; cc < 4; ++cc) {
    const float* cur = buf0 + (cc & 1) * 576;
    float* nxt = buf0 + ((cc + 1) & 1) * 576;
    const int c = wave * 4 + cc;

    __builtin_amdgcn_sched_barrier(0);
    // ---- group 1: ALL x loads for this body (12 VMEM) ----
    f4 v4[2][3];
    f2 v2[2][3];
#pragma unroll
    for (int bo = 0; bo < 2; ++bo) {
      const float* xb = x + ((size_t)(2 * q + bo) * CC + c) * (HH * WW)
                          + (size_t)ho * WW + colbase;
#pragma unroll
      for (int r = 0; r < 3; ++r) {
        v4[bo][r] = *(const f4*)(xb + r * WW);
        v2[bo][r] = *(const f2*)(xb + r * WW + f2off);
      }
    }
    __builtin_amdgcn_sched_barrier(0);
    // ---- group 2: issue stage(cc+1) (9 VMEM) ----
    if (cc < 3) {
      const float* wg = wbase + (size_t)(cc + 1) * (NLOC * 9);
#pragma unroll
      for (int j = 0; j < 9; ++j)
        if (j * 64 + lane < WO * 9)
          async_f32_to_lds(wg + j * 64 + lane, nxt + j * 64);
    }
    __builtin_amdgcn_sched_barrier(0);
    // ---- group 3: stage(cc) landed; x + stage(cc+1) stay in flight ----
    if (cc < 3) {
      asm volatile("s_waitcnt vmcnt(21)");
    } else {
      asm volatile("s_waitcnt vmcnt(12)");
    }
    __builtin_amdgcn_sched_barrier(0);

    // ---- group 4: weights from LDS + FMAs ----
    f4 wq[9];
#pragma unroll
    for (int k = 0; k < 9; ++k)
      wq[k] = *(const f4*)(cur + 36 * l + 4 * k);

#pragma unroll
    for (int bo = 0; bo < 2; ++bo) {
#pragma unroll
      for (int w4 = 0; w4 < 4; ++w4) {
        float s = 0.f;
#pragma unroll
        for (int r = 0; r < 3; ++r) {
#pragma unroll
          for (int j = 0; j < 3; ++j) {
            const int e = w4 + j;                 // 0..5, compile-time
            const int wi = w4 * 9 + r * 3 + j;    // 0..35, compile-time
            const float xv = (e < 4) ? v4[bo][r][e] : v2[bo][r][e - 4];
            s += xv * wq[wi >> 2][wi & 3];
          }
        }
        acc[bo][w4] += s;
      }
    }
  }

  // ---- stash partials into this wave's buf0 (body3 read buf1; stage3 was
  // drained at body3's vmcnt(12); stash is ordered after wq reads by data dep)
#pragma unroll
  for (int bo = 0; bo < 2; ++bo)
    *(f4*)(buf0 + (2 * q + bo) * 64 + colbase) = acc[bo];
  __syncthreads();  // the only block-wide barrier

  // ---- reduce 4 wave-partials, add bias, coalesced store ----
  for (int p = tid; p < 512; p += 256) {
    const int b  = p >> 6;
    const int wo = p & 63;
    if (wo < WO) {
      float s = smem[0 * 1152 + p] + smem[1 * 1152 + p]
              + smem[2 * 1152 + p] + smem[3 * 1152 + p];
      const int loc = o * NLOC + ho * WO + wo;
      out[(size_t)b * TOTAL + loc] = s + bias[loc];
    }
  }
}

extern "C" void kernel_launch(void* const* d_in, const int* in_sizes, int n_in,
                              void* d_out, int out_size, void* d_ws, size_t ws_size,
                              hipStream_t stream) {
  const float* x = (const float*)d_in[0];
  const float* w = (const float*)d_in[1];
  const float* bias = (const float*)d_in[2];
  float* out = (float*)d_out;

  hipLaunchKernelGGL(lc2d_kernel, dim3(OO * HO), dim3(256), 0, stream,
                     x, w, bias, out);
}